// Round 10
// baseline (317.804 us; speedup 1.0000x reference)
//
#include <hip/hip_runtime.h>
#include <hip/hip_fp16.h>

using f32x4  = __attribute__((ext_vector_type(4))) float;
using short8 = __attribute__((ext_vector_type(8))) short;
using ushort4_t = __attribute__((ext_vector_type(4))) unsigned short;

#define XP 136  // padded LDS pitch in bf16 elems
#define LOG2E 1.4426950408889634f

static __device__ __forceinline__ unsigned short f2bf(float f) {
  union { float f; unsigned u; } c; c.f = f;
  unsigned u = c.u;
  return (unsigned short)((u + 0x7fffu + ((u >> 16) & 1u)) >> 16);  // RNE
}
static __device__ __forceinline__ float bf2f(unsigned short b) {
  union { unsigned u; float f; } c; c.u = ((unsigned)b) << 16;
  return c.f;
}

// edge_index may arrive as int64 (reference dtype) or int32 (harness downcast).
__global__ __launch_bounds__(64) void k_detect(const void* ei, int nnodes, int* flag) {
  const long long* e64 = (const long long*)ei;
  long long v = e64[threadIdx.x];
  int ok = (v >= 0 && v < (long long)nnodes) ? 1 : 0;
  unsigned long long m = __ballot(ok);
  if (threadIdx.x == 0) *flag = (m == ~0ull) ? 1 : 0;
}

// K1: h = x @ W (bf16 MFMA, f32 accum), h stored bf16.
// Epilogue computes ssrc/sdst[n][4] (PRE-SCALED by log2e) via butterfly reduce.
__global__ __launch_bounds__(256) void k_gemm(const float* __restrict__ x,
                                              const float* __restrict__ W,
                                              const float* __restrict__ a,
                                              unsigned short* __restrict__ hbf,
                                              float* __restrict__ ssrc,
                                              float* __restrict__ sdst, int nnodes) {
  __shared__ __align__(16) unsigned short lx[64 * XP];
  __shared__ __align__(16) unsigned short lw[128 * XP];
  const int tid = threadIdx.x;
  const int n0 = blockIdx.x * 64;

  for (int it = 0; it < 8; ++it) {
    int idx = tid + it * 256;
    int r = idx >> 5, i4 = idx & 31;
    int n = n0 + r;
    float4 v = make_float4(0.f, 0.f, 0.f, 0.f);
    if (n < nnodes) v = *(const float4*)(x + (size_t)n * 128 + i4 * 4);
    ushort4_t b; b.x = f2bf(v.x); b.y = f2bf(v.y); b.z = f2bf(v.z); b.w = f2bf(v.w);
    *(ushort4_t*)&lx[r * XP + i4 * 4] = b;
  }
  for (int it = 0; it < 64; ++it) {
    int idx = tid + it * 256;
    int hh = idx >> 12, i = (idx >> 5) & 127, o = idx & 31;
    int col = hh * 32 + o;
    lw[col * XP + i] = f2bf(W[idx]);
  }
  __syncthreads();

  const int wave = tid >> 6, lane = tid & 63;
  const int m0 = wave * 16;
  const int lr = lane & 15, lh = lane >> 4;

  f32x4 acc[8] = {};
  for (int kk = 0; kk < 4; ++kk) {
    short8 av = *(const short8*)&lx[(m0 + lr) * XP + kk * 32 + lh * 8];
#pragma unroll
    for (int f = 0; f < 8; ++f) {
      short8 bv = *(const short8*)&lw[(f * 16 + lr) * XP + kk * 32 + lh * 8];
      acc[f] = __builtin_amdgcn_mfma_f32_16x16x32_bf16(av, bv, acc[f], 0, 0, 0);
    }
  }

  float avc[4][4];
#pragma unroll
  for (int hh = 0; hh < 4; ++hh) {
    avc[hh][0] = a[hh * 64 + lr];
    avc[hh][1] = a[hh * 64 + 16 + lr];
    avc[hh][2] = a[hh * 64 + 32 + lr];
    avc[hh][3] = a[hh * 64 + 48 + lr];
  }

#pragma unroll
  for (int j = 0; j < 4; ++j) {
    int n = n0 + m0 + lh * 4 + j;
#pragma unroll
    for (int f = 0; f < 8; ++f) {
      if (n < nnodes) hbf[(size_t)n * 128 + f * 16 + lr] = f2bf(acc[f][j]);
    }
#pragma unroll
    for (int hh = 0; hh < 4; ++hh) {
      float s0 = acc[2 * hh][j] * avc[hh][0] + acc[2 * hh + 1][j] * avc[hh][1];
      float s1 = acc[2 * hh][j] * avc[hh][2] + acc[2 * hh + 1][j] * avc[hh][3];
#pragma unroll
      for (int m = 1; m < 16; m <<= 1) {
        s0 += __shfl_xor(s0, m);
        s1 += __shfl_xor(s1, m);
      }
      if (lr == hh && n < nnodes) {
        ssrc[(size_t)n * 4 + hh] = s0 * LOG2E;   // pre-scaled for exp2
        sdst[(size_t)n * 4 + hh] = s1 * LOG2E;
      }
    }
  }
}

// ---- single-pass multisplit: bucket edges by dst range (8 XCD buckets),
// block-level LDS aggregation -> 256B-contiguous bucket writes (no write amp).
// Bucket mapping affects ONLY locality, never correctness (cursor is global).
__global__ __launch_bounds__(256) void k_prep(const void* __restrict__ ei, const int* __restrict__ flag,
                                              uint2* __restrict__ bkt, int* __restrict__ bcur,
                                              int* __restrict__ deg, int E, int M, int CAP) {
  __shared__ int lcnt[8], lbase[8];
  int t = threadIdx.x;
  if (t < 8) lcnt[t] = 0;
  __syncthreads();
  int e = blockIdx.x * 256 + t;
  int s = 0, d = 0, b = 0, my = 0;
  if (e < E) {
    int is64 = *flag;
    if (is64) {
      s = (int)((const long long*)ei)[e];
      d = (int)((const long long*)ei)[(size_t)E + e];
    } else {
      s = ((const int*)ei)[e];
      d = ((const int*)ei)[(size_t)E + e];
    }
    b = (int)(((unsigned long long)(unsigned)d * (unsigned)M) >> 30);  // ~ d/K
    b &= 7;
    my = atomicAdd(&lcnt[b], 1);
  }
  __syncthreads();
  if (t < 8 && lcnt[t] > 0) lbase[t] = atomicAdd(&bcur[t], lcnt[t]);
  __syncthreads();
  if (e < E) {
    int pos = lbase[b] + my;
    if (pos < CAP) bkt[(size_t)b * CAP + pos] = make_uint2((unsigned)s, (unsigned)d);
    atomicAdd(&deg[d], 1);
  }
}

__global__ __launch_bounds__(256) void k_scan1(const int* __restrict__ deg, int* __restrict__ rowstart,
                                               int* __restrict__ bsum, int N) {
  __shared__ int l[256];
  int t = threadIdx.x;
  int gid = blockIdx.x * 256 + t;
  int v = (gid < N) ? deg[gid] : 0;
  l[t] = v;
  __syncthreads();
  for (int off = 1; off < 256; off <<= 1) {
    int u = (t >= off) ? l[t - off] : 0;
    __syncthreads();
    l[t] += u;
    __syncthreads();
  }
  if (gid < N) rowstart[gid] = l[t] - v;
  if (t == 255) bsum[blockIdx.x] = l[255];
}

__global__ __launch_bounds__(512) void k_scan2(int* __restrict__ bsum, int nb) {
  __shared__ int l[512];
  int t = threadIdx.x;
  int v = (t < nb) ? bsum[t] : 0;
  l[t] = v;
  __syncthreads();
  for (int off = 1; off < 512; off <<= 1) {
    int u = (t >= off) ? l[t - off] : 0;
    __syncthreads();
    l[t] += u;
    __syncthreads();
  }
  if (t < nb) bsum[t] = l[t] - v;
}

__global__ __launch_bounds__(256) void k_scan3(int* __restrict__ rowstart, const int* __restrict__ bsum,
                                               int* __restrict__ cursor, int N) {
  int gid = blockIdx.x * 256 + threadIdx.x;
  if (gid < N) {
    int r = rowstart[gid] + bsum[blockIdx.x];
    rowstart[gid] = r;
    cursor[gid] = r;
  }
}

// Scatter from per-XCD buckets: block p%8 reads ONLY bucket p%8 (sequential 8B)
// and writes eidx within that bucket's ~0.8MB dst window (R4-proven no-amp).
__global__ __launch_bounds__(256) void k_scatter(const uint2* __restrict__ bkt,
                                                 const int* __restrict__ bcur,
                                                 int* __restrict__ cursor,
                                                 int* __restrict__ eidx, int CAP) {
  const int b = blockIdx.x & 7;
  int cnt = bcur[b];
  if (cnt > CAP) cnt = CAP;
  const uint2* mybkt = bkt + (size_t)b * CAP;
  const int stride = (gridDim.x >> 3) * 256;
  for (int i = (blockIdx.x >> 3) * 256 + threadIdx.x; i < cnt; i += stride) {
    uint2 ed = mybkt[i];
    int pos = atomicAdd(&cursor[(int)ed.y], 1);
    eidx[pos] = (int)ed.x;
  }
}

// ---- gather: one wave per dst; bf16 h; p computed once per (edge,head) on
// lanes 0-31 and broadcast via shfl; 8-deep MLP ----
__global__ __launch_bounds__(256) void k_gather(const unsigned short* __restrict__ hbf,
                                                const int* __restrict__ rowstart,
                                                const int* __restrict__ deg,
                                                const int* __restrict__ eidx,
                                                const float* __restrict__ ssrc,
                                                const float* __restrict__ sdst,
                                                float* __restrict__ out, int N) {
  int wid = (blockIdx.x * 256 + threadIdx.x) >> 6;
  int lane = threadIdx.x & 63;
  if (wid >= N) return;
  const int dst = wid;
  const int beg = rowstart[dst];
  const int end = beg + deg[dst];
  const int hh = lane >> 4;              // head of this lane's col pair
  const int lq = lane & 3;               // p-compute: head index
  const int le = lane >> 2;              // p-compute: edge offset within group
  const float sdP = sdst[(size_t)dst * 4 + lq];
  const float sdH = sdst[(size_t)dst * 4 + hh];
  const unsigned* __restrict__ h32 = (const unsigned*)hbf;
  float acc0 = 0.f, acc1 = 0.f, ps = 0.f;

  int i = beg;
  for (; i + 7 < end; i += 8) {
    int s0 = eidx[i + 0], s1 = eidx[i + 1], s2 = eidx[i + 2], s3 = eidx[i + 3];
    int s4 = eidx[i + 4], s5 = eidx[i + 5], s6 = eidx[i + 6], s7 = eidx[i + 7];
    int ip = i + le; ip = (ip < end) ? ip : (end - 1);
    int sP = eidx[ip];
    float ev = ssrc[(size_t)sP * 4 + lq] + sdP;
    ev = fmaxf(ev, 0.2f * ev);
    float pv = exp2f(ev);
    unsigned hv0 = h32[((unsigned)s0 << 6) | (unsigned)lane];
    unsigned hv1 = h32[((unsigned)s1 << 6) | (unsigned)lane];
    unsigned hv2 = h32[((unsigned)s2 << 6) | (unsigned)lane];
    unsigned hv3 = h32[((unsigned)s3 << 6) | (unsigned)lane];
    unsigned hv4 = h32[((unsigned)s4 << 6) | (unsigned)lane];
    unsigned hv5 = h32[((unsigned)s5 << 6) | (unsigned)lane];
    unsigned hv6 = h32[((unsigned)s6 << 6) | (unsigned)lane];
    unsigned hv7 = h32[((unsigned)s7 << 6) | (unsigned)lane];
    float p0 = __shfl(pv, (0 << 2) | hh);
    float p1 = __shfl(pv, (1 << 2) | hh);
    float p2 = __shfl(pv, (2 << 2) | hh);
    float p3 = __shfl(pv, (3 << 2) | hh);
    float p4 = __shfl(pv, (4 << 2) | hh);
    float p5 = __shfl(pv, (5 << 2) | hh);
    float p6 = __shfl(pv, (6 << 2) | hh);
    float p7 = __shfl(pv, (7 << 2) | hh);
    acc0 += p0 * bf2f((unsigned short)(hv0 & 0xffff));
    acc1 += p0 * bf2f((unsigned short)(hv0 >> 16));
    acc0 += p1 * bf2f((unsigned short)(hv1 & 0xffff));
    acc1 += p1 * bf2f((unsigned short)(hv1 >> 16));
    acc0 += p2 * bf2f((unsigned short)(hv2 & 0xffff));
    acc1 += p2 * bf2f((unsigned short)(hv2 >> 16));
    acc0 += p3 * bf2f((unsigned short)(hv3 & 0xffff));
    acc1 += p3 * bf2f((unsigned short)(hv3 >> 16));
    acc0 += p4 * bf2f((unsigned short)(hv4 & 0xffff));
    acc1 += p4 * bf2f((unsigned short)(hv4 >> 16));
    acc0 += p5 * bf2f((unsigned short)(hv5 & 0xffff));
    acc1 += p5 * bf2f((unsigned short)(hv5 >> 16));
    acc0 += p6 * bf2f((unsigned short)(hv6 & 0xffff));
    acc1 += p6 * bf2f((unsigned short)(hv6 >> 16));
    acc0 += p7 * bf2f((unsigned short)(hv7 & 0xffff));
    acc1 += p7 * bf2f((unsigned short)(hv7 >> 16));
    ps += ((p0 + p1) + (p2 + p3)) + ((p4 + p5) + (p6 + p7));
  }
  for (; i < end; ++i) {
    int s = eidx[i];
    unsigned hv = h32[((unsigned)s << 6) | (unsigned)lane];
    float ev = ssrc[(size_t)s * 4 + hh] + sdH;
    ev = fmaxf(ev, 0.2f * ev);
    float p = exp2f(ev);
    acc0 += p * bf2f((unsigned short)(hv & 0xffff));
    acc1 += p * bf2f((unsigned short)(hv >> 16));
    ps += p;
  }
  float r = (ps > 0.f) ? 1.f / ps : 0.f;
  __builtin_nontemporal_store(acc0 * r, out + (size_t)dst * 128 + lane * 2);
  __builtin_nontemporal_store(acc1 * r, out + (size_t)dst * 128 + lane * 2 + 1);
}

extern "C" void kernel_launch(void* const* d_in, const int* in_sizes, int n_in,
                              void* d_out, int out_size, void* d_ws, size_t ws_size,
                              hipStream_t stream) {
  const float* x = (const float*)d_in[0];
  const void*  ei = d_in[1];
  const float* W = (const float*)d_in[2];
  const float* a = (const float*)d_in[3];
  float* out = (float*)d_out;

  const int N = in_sizes[0] / 128;
  const int E = in_sizes[1] / 2;
  const int NB = (N + 255) / 256;              // scan blocks (<=512)
  const int K = (N + 7) / 8;                   // dsts per bucket
  const int M = (int)((1u << 30) / (unsigned)K + 1u);  // magic for d/K
  const int CAP = E / 4;                       // per-bucket capacity (~2x avg)

  char* ws = (char*)d_ws;
  unsigned short* hbf = (unsigned short*)ws;             ws += (size_t)N * 128 * 2;
  float* ssrc     = (float*)ws;                          ws += (size_t)N * 4 * 4;
  float* sdst     = (float*)ws;                          ws += (size_t)N * 4 * 4;
  int*   deg      = (int*)ws;                            ws += (size_t)N * 4;
  int*   bcur     = (int*)ws;                            ws += 8 * 4;
  int*   rowstart = (int*)ws;                            ws += (size_t)N * 4;
  int*   cursor   = (int*)ws;                            ws += (size_t)N * 4;
  int*   bsum     = (int*)ws;                            ws += 512 * 4;
  int*   eidx     = (int*)ws;                            ws += (size_t)E * 4;
  int*   flag     = (int*)ws;

  // Bucket arrays aliased into d_out (25.6 MB < 51.2 MB); dead before k_gather
  // overwrites all of d_out. Deterministic: fully rewritten each call.
  uint2* bkt = (uint2*)d_out;

  hipMemsetAsync(deg, 0, (size_t)N * 4 + 8 * 4, stream);  // deg + bcur contiguous

  k_detect<<<1, 64, 0, stream>>>(ei, N, flag);
  k_gemm<<<(N + 63) / 64, 256, 0, stream>>>(x, W, a, hbf, ssrc, sdst, N);
  k_prep<<<(E + 255) / 256, 256, 0, stream>>>(ei, flag, bkt, bcur, deg, E, M, CAP);
  k_scan1<<<NB, 256, 0, stream>>>(deg, rowstart, bsum, N);
  k_scan2<<<1, 512, 0, stream>>>(bsum, NB);
  k_scan3<<<NB, 256, 0, stream>>>(rowstart, bsum, cursor, N);
  k_scatter<<<2048, 256, 0, stream>>>(bkt, bcur, cursor, eidx, CAP);
  k_gather<<<(N + 3) / 4, 256, 0, stream>>>(hbf, rowstart, deg, eidx, ssrc, sdst, out, N);
}

// Round 11
// 244.856 us; speedup vs baseline: 1.2979x; 1.2979x over previous
//
#include <hip/hip_runtime.h>
#include <hip/hip_fp16.h>

using f32x4  = __attribute__((ext_vector_type(4))) float;
using short8 = __attribute__((ext_vector_type(8))) short;

#define XP 136  // padded LDS pitch in bf16 elems
#define LOG2E 1.4426950408889634f

static __device__ __forceinline__ unsigned short f2bf(float f) {
  union { float f; unsigned u; } c; c.f = f;
  unsigned u = c.u;
  return (unsigned short)((u + 0x7fffu + ((u >> 16) & 1u)) >> 16);  // RNE
}
static __device__ __forceinline__ float bf2f(unsigned short b) {
  union { unsigned u; float f; } c; c.u = ((unsigned)b) << 16;
  return c.f;
}

// ---- fused gemm + prep: independent work, interleaved block roles (1:4) so
// prep's atomic latency hides under gemm's MFMA. Roles are wave-uniform.
// gemm: h = x @ W (bf16 MFMA, f32 acc), h stored bf16; epilogue computes
//       ssrc/sdst[n][4] pre-scaled by log2e (butterfly reduce).
// prep: downcast edge_index -> src32/dst32 (aliased in d_out) + deg histogram.
//       int64-vs-int32 detection inlined per block (wave-0 ballot).
__global__ __launch_bounds__(256) void k_gp(const float* __restrict__ x,
                                            const float* __restrict__ W,
                                            const float* __restrict__ a,
                                            const void* __restrict__ ei,
                                            unsigned short* __restrict__ hbf,
                                            float* __restrict__ ssrc,
                                            float* __restrict__ sdst,
                                            int* __restrict__ src32,
                                            int* __restrict__ dst32,
                                            int* __restrict__ deg,
                                            int nnodes, int E, int NG) {
  __shared__ __align__(16) unsigned short lw[128 * XP];  // W^T [col][k]
  __shared__ int sh_is64;
  const int tid = threadIdx.x;
  const unsigned bI = blockIdx.x;

  // role mapping: blockIdx = 5q+r -> r==0: gemm bid q ; r>0: prep bid 4q+r-1.
  // Tail blocks (>= 5*NG) are extra prep blocks.
  int gemm_bid = -1, prep_bid;
  if (bI < 5u * (unsigned)NG) {
    unsigned q = bI / 5u, r = bI % 5u;
    if (r == 0) gemm_bid = (int)q;
    prep_bid = (int)(4u * q + r - 1u);
  } else {
    prep_bid = (int)(4u * (unsigned)NG + (bI - 5u * (unsigned)NG));
  }

  if (gemm_bid >= 0) {
    // ---------------- GEMM role ----------------
    const int n0 = gemm_bid * 64;
    // stage W^T: W global layout [head][i][o] linear = head*4096 + i*32 + o
    for (int it = 0; it < 64; ++it) {
      int idx = tid + it * 256;
      int hh = idx >> 12, i = (idx >> 5) & 127, o = idx & 31;
      lw[(hh * 32 + o) * XP + i] = f2bf(W[idx]);
    }

    const int wave = tid >> 6, lane = tid & 63;
    const int m0 = wave * 16;
    const int lr = lane & 15, lh = lane >> 4;
    const int n = n0 + m0 + lr;          // row this lane's A-fragment comes from
    const bool rowok = n < nnodes;
    const float* xrow = x + (size_t)n * 128;

    // A fragments straight from global (block-exclusive rows; no reuse lost)
    short8 avf[4];
#pragma unroll
    for (int kk = 0; kk < 4; ++kk) {
      float4 u0 = make_float4(0.f, 0.f, 0.f, 0.f), u1 = u0;
      if (rowok) {
        u0 = *(const float4*)(xrow + kk * 32 + lh * 8);
        u1 = *(const float4*)(xrow + kk * 32 + lh * 8 + 4);
      }
      short8 v;
      v[0] = (short)f2bf(u0.x); v[1] = (short)f2bf(u0.y);
      v[2] = (short)f2bf(u0.z); v[3] = (short)f2bf(u0.w);
      v[4] = (short)f2bf(u1.x); v[5] = (short)f2bf(u1.y);
      v[6] = (short)f2bf(u1.z); v[7] = (short)f2bf(u1.w);
      avf[kk] = v;
    }
    __syncthreads();

    f32x4 acc[8] = {};
#pragma unroll
    for (int kk = 0; kk < 4; ++kk) {
#pragma unroll
      for (int f = 0; f < 8; ++f) {
        short8 bv = *(const short8*)&lw[(f * 16 + lr) * XP + kk * 32 + lh * 8];
        acc[f] = __builtin_amdgcn_mfma_f32_16x16x32_bf16(avf[kk], bv, acc[f], 0, 0, 0);
      }
    }

    float avc[4][4];
#pragma unroll
    for (int hh = 0; hh < 4; ++hh) {
      avc[hh][0] = a[hh * 64 + lr];
      avc[hh][1] = a[hh * 64 + 16 + lr];
      avc[hh][2] = a[hh * 64 + 32 + lr];
      avc[hh][3] = a[hh * 64 + 48 + lr];
    }

#pragma unroll
    for (int j = 0; j < 4; ++j) {
      int nn = n0 + m0 + lh * 4 + j;
#pragma unroll
      for (int f = 0; f < 8; ++f) {
        if (nn < nnodes) hbf[(size_t)nn * 128 + f * 16 + lr] = f2bf(acc[f][j]);
      }
#pragma unroll
      for (int hh = 0; hh < 4; ++hh) {
        float s0 = acc[2 * hh][j] * avc[hh][0] + acc[2 * hh + 1][j] * avc[hh][1];
        float s1 = acc[2 * hh][j] * avc[hh][2] + acc[2 * hh + 1][j] * avc[hh][3];
#pragma unroll
        for (int m = 1; m < 16; m <<= 1) {
          s0 += __shfl_xor(s0, m);
          s1 += __shfl_xor(s1, m);
        }
        if (lr == hh && nn < nnodes) {
          ssrc[(size_t)nn * 4 + hh] = s0 * LOG2E;   // pre-scaled for exp2
          sdst[(size_t)nn * 4 + hh] = s1 * LOG2E;
        }
      }
    }
  } else {
    // ---------------- PREP role ----------------
    if (tid < 64) {
      long long v = ((const long long*)ei)[tid];
      int ok = (v >= 0 && v < (long long)nnodes) ? 1 : 0;
      unsigned long long m = __ballot(ok);
      if (tid == 0) sh_is64 = (m == ~0ull) ? 1 : 0;
    }
    __syncthreads();
    const int is64 = sh_is64;
    int e = prep_bid * 256 + tid;
    if (e < E) {
      int s, d;
      if (is64) {
        s = (int)((const long long*)ei)[e];
        d = (int)((const long long*)ei)[(size_t)E + e];
      } else {
        s = ((const int*)ei)[e];
        d = ((const int*)ei)[(size_t)E + e];
      }
      src32[e] = s;
      dst32[e] = d;
      atomicAdd(&deg[d], 1);
    }
  }
}

__global__ __launch_bounds__(256) void k_scan1(const int* __restrict__ deg, int* __restrict__ rowstart,
                                               int* __restrict__ bsum, int N) {
  __shared__ int l[256];
  int t = threadIdx.x;
  int gid = blockIdx.x * 256 + t;
  int v = (gid < N) ? deg[gid] : 0;
  l[t] = v;
  __syncthreads();
  for (int off = 1; off < 256; off <<= 1) {
    int u = (t >= off) ? l[t - off] : 0;
    __syncthreads();
    l[t] += u;
    __syncthreads();
  }
  if (gid < N) rowstart[gid] = l[t] - v;
  if (t == 255) bsum[blockIdx.x] = l[255];
}

__global__ __launch_bounds__(512) void k_scan2(int* __restrict__ bsum, int nb) {
  __shared__ int l[512];
  int t = threadIdx.x;
  int v = (t < nb) ? bsum[t] : 0;
  l[t] = v;
  __syncthreads();
  for (int off = 1; off < 512; off <<= 1) {
    int u = (t >= off) ? l[t - off] : 0;
    __syncthreads();
    l[t] += u;
    __syncthreads();
  }
  if (t < nb) bsum[t] = l[t] - v;
}

__global__ __launch_bounds__(256) void k_scan3(int* __restrict__ rowstart, const int* __restrict__ bsum,
                                               int* __restrict__ cursor, int N) {
  int gid = blockIdx.x * 256 + threadIdx.x;
  if (gid < N) {
    int r = rowstart[gid] + bsum[blockIdx.x];
    rowstart[gid] = r;
    cursor[gid] = r;
  }
}

// Partitioned scatter, eidx ONLY (R4-proven: 0.8MB/XCD write window -> no
// write amplification). Partition count MUST equal 8 (XCD count): fewer
// partitions share eidx lines across L2s and re-amplify.
__global__ __launch_bounds__(256) void k_scatter(const int* __restrict__ src32,
                                                 const int* __restrict__ dst32,
                                                 int* __restrict__ cursor,
                                                 int* __restrict__ eidx, int E, int N) {
  const int part = blockIdx.x & 7;
  const int wblk = blockIdx.x >> 3;
  const int nwb = gridDim.x >> 3;
  const int lo = (int)(((long long)N * part) >> 3);
  const int hi = (int)(((long long)N * (part + 1)) >> 3);
  for (int e = wblk * 256 + threadIdx.x; e < E; e += nwb * 256) {
    int d = dst32[e];
    if (d >= lo && d < hi) {
      int pos = atomicAdd(&cursor[d], 1);
      eidx[pos] = src32[e];
    }
  }
}

// ---- gather: one wave per dst; bf16 h; p computed once per (edge,head) on
// lanes 0-31 and broadcast via shfl; 8-deep MLP ----
__global__ __launch_bounds__(256) void k_gather(const unsigned short* __restrict__ hbf,
                                                const int* __restrict__ rowstart,
                                                const int* __restrict__ deg,
                                                const int* __restrict__ eidx,
                                                const float* __restrict__ ssrc,
                                                const float* __restrict__ sdst,
                                                float* __restrict__ out, int N) {
  int wid = (blockIdx.x * 256 + threadIdx.x) >> 6;
  int lane = threadIdx.x & 63;
  if (wid >= N) return;
  const int dst = wid;
  const int beg = rowstart[dst];
  const int end = beg + deg[dst];
  const int hh = lane >> 4;              // head of this lane's col pair
  const int lq = lane & 3;               // p-compute: head index
  const int le = lane >> 2;              // p-compute: edge offset within group
  const float sdP = sdst[(size_t)dst * 4 + lq];
  const float sdH = sdst[(size_t)dst * 4 + hh];
  const unsigned* __restrict__ h32 = (const unsigned*)hbf;
  float acc0 = 0.f, acc1 = 0.f, ps = 0.f;

  int i = beg;
  for (; i + 7 < end; i += 8) {
    int s0 = eidx[i + 0], s1 = eidx[i + 1], s2 = eidx[i + 2], s3 = eidx[i + 3];
    int s4 = eidx[i + 4], s5 = eidx[i + 5], s6 = eidx[i + 6], s7 = eidx[i + 7];
    int ip = i + le; ip = (ip < end) ? ip : (end - 1);
    int sP = eidx[ip];
    float ev = ssrc[(size_t)sP * 4 + lq] + sdP;
    ev = fmaxf(ev, 0.2f * ev);
    float pv = exp2f(ev);
    unsigned hv0 = h32[((unsigned)s0 << 6) | (unsigned)lane];
    unsigned hv1 = h32[((unsigned)s1 << 6) | (unsigned)lane];
    unsigned hv2 = h32[((unsigned)s2 << 6) | (unsigned)lane];
    unsigned hv3 = h32[((unsigned)s3 << 6) | (unsigned)lane];
    unsigned hv4 = h32[((unsigned)s4 << 6) | (unsigned)lane];
    unsigned hv5 = h32[((unsigned)s5 << 6) | (unsigned)lane];
    unsigned hv6 = h32[((unsigned)s6 << 6) | (unsigned)lane];
    unsigned hv7 = h32[((unsigned)s7 << 6) | (unsigned)lane];
    float p0 = __shfl(pv, (0 << 2) | hh);
    float p1 = __shfl(pv, (1 << 2) | hh);
    float p2 = __shfl(pv, (2 << 2) | hh);
    float p3 = __shfl(pv, (3 << 2) | hh);
    float p4 = __shfl(pv, (4 << 2) | hh);
    float p5 = __shfl(pv, (5 << 2) | hh);
    float p6 = __shfl(pv, (6 << 2) | hh);
    float p7 = __shfl(pv, (7 << 2) | hh);
    acc0 += p0 * bf2f((unsigned short)(hv0 & 0xffff));
    acc1 += p0 * bf2f((unsigned short)(hv0 >> 16));
    acc0 += p1 * bf2f((unsigned short)(hv1 & 0xffff));
    acc1 += p1 * bf2f((unsigned short)(hv1 >> 16));
    acc0 += p2 * bf2f((unsigned short)(hv2 & 0xffff));
    acc1 += p2 * bf2f((unsigned short)(hv2 >> 16));
    acc0 += p3 * bf2f((unsigned short)(hv3 & 0xffff));
    acc1 += p3 * bf2f((unsigned short)(hv3 >> 16));
    acc0 += p4 * bf2f((unsigned short)(hv4 & 0xffff));
    acc1 += p4 * bf2f((unsigned short)(hv4 >> 16));
    acc0 += p5 * bf2f((unsigned short)(hv5 & 0xffff));
    acc1 += p5 * bf2f((unsigned short)(hv5 >> 16));
    acc0 += p6 * bf2f((unsigned short)(hv6 & 0xffff));
    acc1 += p6 * bf2f((unsigned short)(hv6 >> 16));
    acc0 += p7 * bf2f((unsigned short)(hv7 & 0xffff));
    acc1 += p7 * bf2f((unsigned short)(hv7 >> 16));
    ps += ((p0 + p1) + (p2 + p3)) + ((p4 + p5) + (p6 + p7));
  }
  for (; i < end; ++i) {
    int s = eidx[i];
    unsigned hv = h32[((unsigned)s << 6) | (unsigned)lane];
    float ev = ssrc[(size_t)s * 4 + hh] + sdH;
    ev = fmaxf(ev, 0.2f * ev);
    float p = exp2f(ev);
    acc0 += p * bf2f((unsigned short)(hv & 0xffff));
    acc1 += p * bf2f((unsigned short)(hv >> 16));
    ps += p;
  }
  float r = (ps > 0.f) ? 1.f / ps : 0.f;
  __builtin_nontemporal_store(acc0 * r, out + (size_t)dst * 128 + lane * 2);
  __builtin_nontemporal_store(acc1 * r, out + (size_t)dst * 128 + lane * 2 + 1);
}

extern "C" void kernel_launch(void* const* d_in, const int* in_sizes, int n_in,
                              void* d_out, int out_size, void* d_ws, size_t ws_size,
                              hipStream_t stream) {
  const float* x = (const float*)d_in[0];
  const void*  ei = d_in[1];
  const float* W = (const float*)d_in[2];
  const float* a = (const float*)d_in[3];
  float* out = (float*)d_out;

  const int N = in_sizes[0] / 128;
  const int E = in_sizes[1] / 2;
  const int NB = (N + 255) / 256;              // scan blocks (<=512)
  const int NG = (N + 63) / 64;                // gemm blocks
  const int NP = (E + 255) / 256;              // prep blocks
  // interleaved grid: 5*NG covers NG gemm + 4*NG prep; tail for leftover prep
  const int extra = (NP > 4 * NG) ? (NP - 4 * NG) : 0;
  const int TOT = 5 * NG + extra;

  char* ws = (char*)d_ws;
  unsigned short* hbf = (unsigned short*)ws;             ws += (size_t)N * 128 * 2;
  float* ssrc     = (float*)ws;                          ws += (size_t)N * 4 * 4;
  float* sdst     = (float*)ws;                          ws += (size_t)N * 4 * 4;
  int*   deg      = (int*)ws;                            ws += (size_t)N * 4;
  int*   rowstart = (int*)ws;                            ws += (size_t)N * 4;
  int*   cursor   = (int*)ws;                            ws += (size_t)N * 4;
  int*   bsum     = (int*)ws;                            ws += 512 * 4;
  int*   eidx     = (int*)ws;

  // src32/dst32 scratch aliased into d_out (12.8 MB << 51.2 MB); dead before
  // k_gather overwrites all of d_out.
  int* src32 = (int*)d_out;
  int* dst32 = src32 + E;

  hipMemsetAsync(deg, 0, (size_t)N * 4, stream);

  k_gp<<<TOT, 256, 0, stream>>>(x, W, a, ei, hbf, ssrc, sdst, src32, dst32, deg, N, E, NG);
  k_scan1<<<NB, 256, 0, stream>>>(deg, rowstart, bsum, N);
  k_scan2<<<1, 512, 0, stream>>>(bsum, NB);
  k_scan3<<<NB, 256, 0, stream>>>(rowstart, bsum, cursor, N);
  k_scatter<<<2048, 256, 0, stream>>>(src32, dst32, cursor, eidx, E, N);
  k_gather<<<(N + 3) / 4, 256, 0, stream>>>(hbf, rowstart, deg, eidx, ssrc, sdst, out, N);
}